// Round 2
// baseline (244.646 us; speedup 1.0000x reference)
//
#include <hip/hip_runtime.h>

typedef unsigned long long u64;

#define N_PTS   4096
#define B_SZ    4
#define N_PER_B 1024
#define L_TOK   16
#define FV      256
#define FL      768
#define FDIM    128
#define KNN     16
#define RH      64   // rel_encoder hidden

// ---------------- kNN: one wave per query, exact (d2,idx) key selection ----
__global__ __launch_bounds__(64) void knn_kernel(const float* __restrict__ xyz,
                                                 int* __restrict__ knn) {
    int q = blockIdx.x;
    int lane = threadIdx.x;
    int base = (q >> 10) << 10;   // batch start
    float qx = xyz[q * 3 + 0];
    float qy = xyz[q * 3 + 1];
    float qz = xyz[q * 3 + 2];
    u64 keys[16];
#pragma unroll
    for (int m = 0; m < 16; m++) {
        int j = base + lane + (m << 6);
        float dx = qx - xyz[j * 3 + 0];
        float dy = qy - xyz[j * 3 + 1];
        float dz = qz - xyz[j * 3 + 2];
        // match reference rounding: no fma contraction, (x+y) then +z
        float d2 = __fadd_rn(__fadd_rn(__fmul_rn(dx, dx), __fmul_rn(dy, dy)),
                             __fmul_rn(dz, dz));
        keys[m] = (((u64)__float_as_uint(d2)) << 32) | (unsigned int)j;
    }
    for (int r = 0; r < KNN; r++) {
        u64 lmin = keys[0];
#pragma unroll
        for (int m = 1; m < 16; m++) lmin = (keys[m] < lmin) ? keys[m] : lmin;
        u64 g = lmin;
#pragma unroll
        for (int off = 32; off > 0; off >>= 1) {
            u64 o = __shfl_xor(g, off, 64);
            g = (o < g) ? o : g;
        }
#pragma unroll
        for (int m = 0; m < 16; m++)
            if (keys[m] == g) keys[m] = ~0ULL;
        if (lane == 0) knn[q * KNN + r] = (int)(g & 0xffffffffu);
    }
}

// ---------------- lang encoder stage 1: hl = lang @ Wl1 + bl1 --------------
__global__ __launch_bounds__(128) void lang1_kernel(const float* __restrict__ lf,
                                                    const float* __restrict__ Wl1,
                                                    const float* __restrict__ bl1,
                                                    float* __restrict__ hl) {
    __shared__ float lrow[FL];
    int r = blockIdx.x, t = threadIdx.x;
    for (int k = t; k < FL; k += 128) lrow[k] = lf[r * FL + k];
    __syncthreads();
    float acc = bl1[t];
    for (int k = 0; k < FL; k++) acc += lrow[k] * Wl1[k * FDIM + t];
    hl[r * FDIM + t] = acc;
}

// ---------------- lang encoder stage 2: BN + ReLU + GEMM2 ------------------
__global__ __launch_bounds__(128) void lang2_kernel(const float* __restrict__ hl,
                                                    const float* __restrict__ bn_g,
                                                    const float* __restrict__ bn_b,
                                                    const float* __restrict__ Wl2,
                                                    const float* __restrict__ bl2,
                                                    float* __restrict__ lang) {
    __shared__ float rl[64 * FDIM];
    int t = threadIdx.x;
    float s = 0.f, s2 = 0.f;
    for (int r = 0; r < 64; r++) {
        float v = hl[r * FDIM + t];
        s += v; s2 += v * v;
    }
    float mu = s * (1.f / 64.f);
    float var = s2 * (1.f / 64.f) - mu * mu;
    float rs = rsqrtf(var + 1e-5f);
    float g = bn_g[t], bb = bn_b[t];
    for (int r = 0; r < 64; r++) {
        float v = (hl[r * FDIM + t] - mu) * rs * g + bb;
        rl[r * FDIM + t] = fmaxf(v, 0.f);
    }
    __syncthreads();
    float bv = bl2[t];
    for (int r0 = 0; r0 < 64; r0 += 16) {
        float acc[16];
#pragma unroll
        for (int r = 0; r < 16; r++) acc[r] = bv;
        for (int k = 0; k < FDIM; k++) {
            float w = Wl2[k * FDIM + t];
#pragma unroll
            for (int r = 0; r < 16; r++) acc[r] += rl[(r0 + r) * FDIM + k] * w;
        }
#pragma unroll
        for (int r = 0; r < 16; r++) lang[(r0 + r) * FDIM + t] = acc[r];
    }
}

// ---------------- feat encoder + atten logits ------------------------------
__global__ __launch_bounds__(128) void feat_kernel(const float* __restrict__ fin_g,
                                                   const float* __restrict__ W1,
                                                   const float* __restrict__ b1,
                                                   const float* __restrict__ ln_g,
                                                   const float* __restrict__ ln_b,
                                                   const float* __restrict__ W2,
                                                   const float* __restrict__ b2,
                                                   const float* __restrict__ lang,
                                                   float* __restrict__ feats,
                                                   float* __restrict__ atten) {
    __shared__ float fin[FV];
    __shared__ float rbuf[FDIM];
    __shared__ float red[4];
    __shared__ float fb[FDIM];
    __shared__ float pb[FDIM];
    int i = blockIdx.x, t = threadIdx.x;
    fin[t]       = fin_g[i * FV + t];
    fin[t + 128] = fin_g[i * FV + 128 + t];
    __syncthreads();
    float h = b1[t];
    for (int k = 0; k < FV; k++) h += fin[k] * W1[k * FDIM + t];
    // LayerNorm over 128
    float s = h, s2 = h * h;
#pragma unroll
    for (int off = 32; off > 0; off >>= 1) {
        s  += __shfl_xor(s, off, 64);
        s2 += __shfl_xor(s2, off, 64);
    }
    int w = t >> 6;
    if ((t & 63) == 0) { red[w * 2] = s; red[w * 2 + 1] = s2; }
    __syncthreads();
    float S = red[0] + red[2], S2 = red[1] + red[3];
    float mu = S * (1.f / 128.f);
    float var = S2 * (1.f / 128.f) - mu * mu;
    float r = fmaxf((h - mu) * rsqrtf(var + 1e-5f) * ln_g[t] + ln_b[t], 0.f);
    rbuf[t] = r;
    __syncthreads();
    float f = b2[t];
    for (int k = 0; k < FDIM; k++) f += rbuf[k] * W2[k * FDIM + t];
    feats[i * FDIM + t] = f;
    fb[t] = f;
    __syncthreads();
    // atten[i, l] = dot(feats_i, lang[b, l, :]) ; 8 threads per l
    int l = t >> 3, sj = t & 7;
    int bi = i >> 10;
    const float* lrow = lang + (bi * L_TOK + l) * FDIM;
    float p = 0.f;
#pragma unroll
    for (int m = 0; m < 16; m++) {
        int k = sj + (m << 3);
        p += fb[k] * lrow[k];
    }
    pb[t] = p;
    __syncthreads();
    if (t < L_TOK) {
        float a = 0.f;
#pragma unroll
        for (int u = 0; u < 8; u++) a += pb[t * 8 + u];
        atten[i * L_TOK + t] = a;
    }
}

// ---------------- edge kernel: softmax + rel MLP + message sum -------------
__global__ __launch_bounds__(128) void edge_kernel(const float* __restrict__ xyz,
                                                   const float* __restrict__ mask,
                                                   const float* __restrict__ Wr1,
                                                   const float* __restrict__ br1,
                                                   const float* __restrict__ Wr2,
                                                   const float* __restrict__ br2,
                                                   const int* __restrict__ knn,
                                                   const float* __restrict__ lang,
                                                   const float* __restrict__ feats,
                                                   const float* __restrict__ atten,
                                                   float* __restrict__ out) {
    __shared__ int   idx[KNN];
    __shared__ float sat[KNN][L_TOK];
    __shared__ float satt[KNN][L_TOK];
    __shared__ float ls[L_TOK * FDIM];
    __shared__ float ein[KNN][12];
    __shared__ float hid[KNN][RH];
    int i = blockIdx.x, t = threadIdx.x;
    int bi = i >> 10;
    if (t < KNN) idx[t] = knn[i * KNN + t];
    for (int p = t; p < L_TOK * FDIM; p += 128) ls[p] = lang[bi * L_TOK * FDIM + p];
    __syncthreads();
    for (int p = t; p < KNN * L_TOK; p += 128) {
        int e = p >> 4, l = p & 15;
        sat[e][l] = atten[idx[e] * L_TOK + l];
    }
    __syncthreads();
    if (t < L_TOK) {  // per-l: segment max, exp, sum, mask
        int l = t;
        float m = -1e30f;
        for (int e = 0; e < KNN; e++) m = fmaxf(m, sat[e][l]);
        float sum = 0.f;
        for (int e = 0; e < KNN; e++) {
            float a = expf(sat[e][l] - m);
            satt[e][l] = a;
            sum += a;
        }
        float inv = mask[i * L_TOK + l] / sum;
        for (int e = 0; e < KNN; e++) satt[e][l] *= inv;
    }
    __syncthreads();
    if (t < KNN) {  // per-e: normalize over l; build geometric input
        int e = t;
        float s = 0.f;
        for (int l = 0; l < L_TOK; l++) s += satt[e][l];
        float inv = 1.f / (s + 1e-7f);
        for (int l = 0; l < L_TOK; l++) satt[e][l] *= inv;
        int j = idx[e];
        float xi0 = xyz[i * 3 + 0], xi1 = xyz[i * 3 + 1], xi2 = xyz[i * 3 + 2];
        float xj0 = xyz[j * 3 + 0], xj1 = xyz[j * 3 + 1], xj2 = xyz[j * 3 + 2];
        float d0 = xi0 - xj0, d1 = xi1 - xj1, d2v = xi2 - xj2;
        float nr = sqrtf(d0 * d0 + d1 * d1 + d2v * d2v + 1e-12f);
        ein[e][0] = xi0; ein[e][1] = xi1; ein[e][2] = xi2;
        ein[e][3] = xj0; ein[e][4] = xj1; ein[e][5] = xj2;
        ein[e][6] = d0;  ein[e][7] = d1;  ein[e][8] = d2v;
        ein[e][9] = nr;
    }
    __syncthreads();
    for (int p = t; p < KNN * RH; p += 128) {  // rel hidden layer
        int e = p >> 6, hd = p & 63;
        float a = br1[hd];
#pragma unroll
        for (int k = 0; k < 10; k++) a += ein[e][k] * Wr1[k * RH + hd];
        hid[e][hd] = fmaxf(a, 0.f);
    }
    __syncthreads();
    // hoist Wr2 column into registers (reused for all 16 edges)
    float wreg[RH];
#pragma unroll
    for (int k = 0; k < RH; k++) wreg[k] = Wr2[k * FDIM + t];
    float br2v = br2[t];
    float acc = 0.f;
    for (int e = 0; e < KNN; e++) {
        float ew = br2v;
#pragma unroll
        for (int k = 0; k < RH; k++) ew += hid[e][k] * wreg[k];
        float ctx = 0.f;
#pragma unroll
        for (int l = 0; l < L_TOK; l++) ctx += satt[e][l] * ls[l * FDIM + t];
        float fj = feats[idx[e] * FDIM + t];
        acc += fj * ctx * ew;
    }
    out[i * FDIM + t] = feats[i * FDIM + t] + acc;
}

extern "C" void kernel_launch(void* const* d_in, const int* in_sizes, int n_in,
                              void* d_out, int out_size, void* d_ws, size_t ws_size,
                              hipStream_t stream) {
    const float* xyz   = (const float*)d_in[0];
    // d_in[1] = batch_index (int32) — layout-implied (i>>10), unused
    const float* features = (const float*)d_in[2];
    const float* lang_f   = (const float*)d_in[3];
    const float* mask     = (const float*)d_in[4];
    const float* W1   = (const float*)d_in[5];
    const float* b1   = (const float*)d_in[6];
    const float* ln_g = (const float*)d_in[7];
    const float* ln_b = (const float*)d_in[8];
    const float* W2   = (const float*)d_in[9];
    const float* b2   = (const float*)d_in[10];
    const float* Wl1  = (const float*)d_in[11];
    const float* bl1  = (const float*)d_in[12];
    const float* bn_g = (const float*)d_in[13];
    const float* bn_b = (const float*)d_in[14];
    const float* Wl2  = (const float*)d_in[15];
    const float* bl2  = (const float*)d_in[16];
    const float* Wr1  = (const float*)d_in[17];
    const float* br1  = (const float*)d_in[18];
    const float* Wr2  = (const float*)d_in[19];
    const float* br2  = (const float*)d_in[20];

    float* ws_feats = (float*)d_ws;                       // N*F
    float* ws_atten = ws_feats + N_PTS * FDIM;            // N*L
    float* ws_lang  = ws_atten + N_PTS * L_TOK;           // B*L*F
    float* ws_hl    = ws_lang + B_SZ * L_TOK * FDIM;      // 64*F
    int*   ws_knn   = (int*)(ws_hl + 64 * FDIM);          // N*K

    knn_kernel<<<N_PTS, 64, 0, stream>>>(xyz, ws_knn);
    lang1_kernel<<<B_SZ * L_TOK, 128, 0, stream>>>(lang_f, Wl1, bl1, ws_hl);
    lang2_kernel<<<1, 128, 0, stream>>>(ws_hl, bn_g, bn_b, Wl2, bl2, ws_lang);
    feat_kernel<<<N_PTS, 128, 0, stream>>>(features, W1, b1, ln_g, ln_b, W2, b2,
                                           ws_lang, ws_feats, ws_atten);
    edge_kernel<<<N_PTS, 128, 0, stream>>>(xyz, mask, Wr1, br1, Wr2, br2,
                                           ws_knn, ws_lang, ws_feats, ws_atten,
                                           (float*)d_out);
}

// Round 3
// 194.485 us; speedup vs baseline: 1.2579x; 1.2579x over previous
//
#include <hip/hip_runtime.h>

typedef unsigned long long u64;

#define N_PTS   4096
#define B_SZ    4
#define N_PER_B 1024
#define L_TOK   16
#define FV      256
#define FL      768
#define FDIM    128
#define KNN     16
#define RH      64   // rel_encoder hidden

// =====================================================================
// K1: fused independent work. 256-thread blocks, specialized by range:
//   [0,1024)     knn, 4 queries/block (one wave each)
//   [1024,2048)  feat encoder, 4 points/block
//   [2048,2112)  lang encoder stage 1, 1 row/block (split-k 2)
// =====================================================================
__global__ __launch_bounds__(256) void k1_kernel(const float* __restrict__ xyz,
                                                 const float* __restrict__ features,
                                                 const float* __restrict__ lf,
                                                 const float* __restrict__ W1,
                                                 const float* __restrict__ b1,
                                                 const float* __restrict__ ln_g,
                                                 const float* __restrict__ ln_b,
                                                 const float* __restrict__ W2,
                                                 const float* __restrict__ b2,
                                                 const float* __restrict__ Wl1,
                                                 const float* __restrict__ bl1,
                                                 int* __restrict__ knn,
                                                 float* __restrict__ feats,
                                                 float* __restrict__ hl) {
    __shared__ float smem[4 * 256 + 4 * 128 + 16];
    int b = blockIdx.x, t = threadIdx.x;

    if (b < 1024) {
        // ---------------- kNN: one wave per query ----------------
        int lane = t & 63;
        int q = b * 4 + (t >> 6);
        int base = (q >> 10) << 10;
        float qx = xyz[q * 3 + 0];
        float qy = xyz[q * 3 + 1];
        float qz = xyz[q * 3 + 2];
        u64 keys[16];
#pragma unroll
        for (int m = 0; m < 16; m++) {
            int j = base + lane + (m << 6);
            float dx = qx - xyz[j * 3 + 0];
            float dy = qy - xyz[j * 3 + 1];
            float dz = qz - xyz[j * 3 + 2];
            // match reference rounding: no fma contraction, (x+y) then +z
            float d2 = __fadd_rn(__fadd_rn(__fmul_rn(dx, dx), __fmul_rn(dy, dy)),
                                 __fmul_rn(dz, dz));
            keys[m] = (((u64)__float_as_uint(d2)) << 32) | (unsigned int)j;
        }
        for (int r = 0; r < KNN; r++) {
            u64 lmin = keys[0];
#pragma unroll
            for (int m = 1; m < 16; m++) lmin = (keys[m] < lmin) ? keys[m] : lmin;
            u64 g = lmin;
#pragma unroll
            for (int off = 32; off > 0; off >>= 1) {
                u64 o = __shfl_xor(g, off, 64);
                g = (o < g) ? o : g;
            }
#pragma unroll
            for (int m = 0; m < 16; m++)
                if (keys[m] == g) keys[m] = ~0ULL;
            if (lane == 0) knn[q * KNN + r] = (int)(g & 0xffffffffu);
        }
    } else if (b < 2048) {
        // ---------------- feat encoder: 4 points/block ----------------
        int i0 = (b - 1024) * 4;
        float* fin  = smem;              // [4][256]
        float* rbuf = smem + 1024;       // [4][128]
        float* red  = smem + 1536;       // [4 waves][4]
        for (int p = t; p < 4 * FV; p += 256) {
            int pp = p >> 8, k = p & 255;
            fin[pp * FV + k] = features[(i0 + pp) * FV + k];
        }
        __syncthreads();
        int c = t & 127, h = t >> 7;
        int p0 = 2 * h, p1 = 2 * h + 1;
        float bv = b1[c];
        float acc0 = bv, acc1 = bv;
        for (int k = 0; k < FV; k++) {
            float w = W1[k * FDIM + c];
            acc0 += fin[p0 * FV + k] * w;
            acc1 += fin[p1 * FV + k] * w;
        }
        // LayerNorm over the 128 columns of each point (2 waves per half)
        float s0 = acc0, q0 = acc0 * acc0, s1 = acc1, q1 = acc1 * acc1;
#pragma unroll
        for (int off = 32; off > 0; off >>= 1) {
            s0 += __shfl_xor(s0, off, 64);
            q0 += __shfl_xor(q0, off, 64);
            s1 += __shfl_xor(s1, off, 64);
            q1 += __shfl_xor(q1, off, 64);
        }
        int wid = t >> 6;
        if ((t & 63) == 0) {
            red[wid * 4 + 0] = s0; red[wid * 4 + 1] = q0;
            red[wid * 4 + 2] = s1; red[wid * 4 + 3] = q1;
        }
        __syncthreads();
        float S0 = red[(2 * h) * 4 + 0] + red[(2 * h + 1) * 4 + 0];
        float Q0 = red[(2 * h) * 4 + 1] + red[(2 * h + 1) * 4 + 1];
        float S1 = red[(2 * h) * 4 + 2] + red[(2 * h + 1) * 4 + 2];
        float Q1 = red[(2 * h) * 4 + 3] + red[(2 * h + 1) * 4 + 3];
        float g = ln_g[c], bb = ln_b[c];
        float mu0 = S0 * (1.f / 128.f), var0 = Q0 * (1.f / 128.f) - mu0 * mu0;
        float mu1 = S1 * (1.f / 128.f), var1 = Q1 * (1.f / 128.f) - mu1 * mu1;
        float r0 = fmaxf((acc0 - mu0) * rsqrtf(var0 + 1e-5f) * g + bb, 0.f);
        float r1 = fmaxf((acc1 - mu1) * rsqrtf(var1 + 1e-5f) * g + bb, 0.f);
        rbuf[p0 * FDIM + c] = r0;
        rbuf[p1 * FDIM + c] = r1;
        __syncthreads();
        float b2v = b2[c];
        float f0 = b2v, f1 = b2v;
        for (int k = 0; k < FDIM; k++) {
            float w = W2[k * FDIM + c];
            f0 += rbuf[p0 * FDIM + k] * w;
            f1 += rbuf[p1 * FDIM + k] * w;
        }
        feats[(i0 + p0) * FDIM + c] = f0;
        feats[(i0 + p1) * FDIM + c] = f1;
    } else {
        // ---------------- lang stage 1: hl = lang_row @ Wl1 + bl1 ------
        int r = b - 2048;
        float* lrow = smem;          // [768]
        float* part = smem + 768;    // [2][128]
        for (int k = t; k < FL; k += 256) lrow[k] = lf[r * FL + k];
        __syncthreads();
        int c = t & 127, kh = t >> 7;
        float acc = (kh == 0) ? bl1[c] : 0.f;
        int k0 = kh * 384;
        for (int k = k0; k < k0 + 384; k++) acc += lrow[k] * Wl1[k * FDIM + c];
        part[kh * FDIM + c] = acc;
        __syncthreads();
        if (kh == 0) hl[r * FDIM + c] = part[c] + part[FDIM + c];
    }
}

// =====================================================================
// K2: lang stage 2 — BN (batch stats) + ReLU + GEMM2. 16 blocks × 4 rows.
// =====================================================================
__global__ __launch_bounds__(128) void lang2_kernel(const float* __restrict__ hl,
                                                    const float* __restrict__ bn_g,
                                                    const float* __restrict__ bn_b,
                                                    const float* __restrict__ Wl2,
                                                    const float* __restrict__ bl2,
                                                    float* __restrict__ lang) {
    __shared__ float rl4[4][FDIM];
    int t = threadIdx.x;
    int r0 = blockIdx.x * 4;
    float s = 0.f, s2 = 0.f;
    for (int r = 0; r < 64; r++) {
        float v = hl[r * FDIM + t];
        s += v; s2 += v * v;
    }
    float mu = s * (1.f / 64.f);
    float var = s2 * (1.f / 64.f) - mu * mu;
    float rs = rsqrtf(var + 1e-5f);
    float g = bn_g[t], bb = bn_b[t];
#pragma unroll
    for (int p = 0; p < 4; p++)
        rl4[p][t] = fmaxf((hl[(r0 + p) * FDIM + t] - mu) * rs * g + bb, 0.f);
    __syncthreads();
    float bv = bl2[t];
    float a0 = bv, a1 = bv, a2 = bv, a3 = bv;
    for (int k = 0; k < FDIM; k++) {
        float w = Wl2[k * FDIM + t];
        a0 += rl4[0][k] * w;
        a1 += rl4[1][k] * w;
        a2 += rl4[2][k] * w;
        a3 += rl4[3][k] * w;
    }
    lang[(r0 + 0) * FDIM + t] = a0;
    lang[(r0 + 1) * FDIM + t] = a1;
    lang[(r0 + 2) * FDIM + t] = a2;
    lang[(r0 + 3) * FDIM + t] = a3;
}

// =====================================================================
// K3: attention logits atten[i,l] = feats_i · lang[b_i, l]. 2 points/block.
// =====================================================================
__global__ __launch_bounds__(256) void atten_kernel(const float* __restrict__ feats,
                                                    const float* __restrict__ lang,
                                                    float* __restrict__ atten) {
    __shared__ float fb[2][FDIM];
    __shared__ float pb[256];
    int t = threadIdx.x;
    int half = t >> 7, tt = t & 127;
    int i = blockIdx.x * 2 + half;
    fb[half][tt] = feats[i * FDIM + tt];
    __syncthreads();
    int l = tt >> 3, sj = tt & 7;
    int bi = i >> 10;
    const float* lrow = lang + (bi * L_TOK + l) * FDIM;
    float p = 0.f;
#pragma unroll
    for (int m = 0; m < 16; m++) {
        int k = sj + (m << 3);
        p += fb[half][k] * lrow[k];
    }
    pb[t] = p;
    __syncthreads();
    if (tt < L_TOK) {
        float a = 0.f;
#pragma unroll
        for (int u = 0; u < 8; u++) a += pb[half * 128 + tt * 8 + u];
        atten[i * L_TOK + tt] = a;
    }
}

// =====================================================================
// K4: edge kernel — segment softmax + rel MLP + message sum.
// Registers: lang column (16) + Wr2 column (64); float4 LDS broadcasts.
// =====================================================================
__global__ __launch_bounds__(128) void edge_kernel(const float* __restrict__ xyz,
                                                   const float* __restrict__ mask,
                                                   const float* __restrict__ Wr1,
                                                   const float* __restrict__ br1,
                                                   const float* __restrict__ Wr2,
                                                   const float* __restrict__ br2,
                                                   const int* __restrict__ knn,
                                                   const float* __restrict__ lang,
                                                   const float* __restrict__ feats,
                                                   const float* __restrict__ atten,
                                                   float* __restrict__ out) {
    __shared__ int   idx[KNN];
    __shared__ float sat[KNN][L_TOK];
    __shared__ float satt[KNN][L_TOK];
    __shared__ float ein[KNN][12];
    __shared__ float hid[KNN][RH];
    int i = blockIdx.x, t = threadIdx.x;
    int bi = i >> 10;
    if (t < KNN) idx[t] = knn[i * KNN + t];
    // lang tile column and Wr2 column into registers
    float lsreg[L_TOK];
    const float* lb = lang + bi * L_TOK * FDIM + t;
#pragma unroll
    for (int l = 0; l < L_TOK; l++) lsreg[l] = lb[l * FDIM];
    float wreg[RH];
#pragma unroll
    for (int k = 0; k < RH; k++) wreg[k] = Wr2[k * FDIM + t];
    __syncthreads();
    for (int p = t; p < KNN * L_TOK; p += 128) {
        int e = p >> 4, l = p & 15;
        sat[e][l] = atten[idx[e] * L_TOK + l];
    }
    __syncthreads();
    if (t < L_TOK) {  // per-l: segment max, exp, sum, mask
        int l = t;
        float m = -1e30f;
        for (int e = 0; e < KNN; e++) m = fmaxf(m, sat[e][l]);
        float sum = 0.f;
        for (int e = 0; e < KNN; e++) {
            float a = expf(sat[e][l] - m);
            satt[e][l] = a;
            sum += a;
        }
        float inv = mask[i * L_TOK + l] / sum;
        for (int e = 0; e < KNN; e++) satt[e][l] *= inv;
    }
    __syncthreads();
    if (t < KNN) {  // per-e: normalize over l; build geometric input
        int e = t;
        float s = 0.f;
        for (int l = 0; l < L_TOK; l++) s += satt[e][l];
        float inv = 1.f / (s + 1e-7f);
        for (int l = 0; l < L_TOK; l++) satt[e][l] *= inv;
        int j = idx[e];
        float xi0 = xyz[i * 3 + 0], xi1 = xyz[i * 3 + 1], xi2 = xyz[i * 3 + 2];
        float xj0 = xyz[j * 3 + 0], xj1 = xyz[j * 3 + 1], xj2 = xyz[j * 3 + 2];
        float d0 = xi0 - xj0, d1 = xi1 - xj1, d2v = xi2 - xj2;
        float nr = sqrtf(d0 * d0 + d1 * d1 + d2v * d2v + 1e-12f);
        ein[e][0] = xi0; ein[e][1] = xi1; ein[e][2] = xi2;
        ein[e][3] = xj0; ein[e][4] = xj1; ein[e][5] = xj2;
        ein[e][6] = d0;  ein[e][7] = d1;  ein[e][8] = d2v;
        ein[e][9] = nr;
    }
    __syncthreads();
    for (int p = t; p < KNN * RH; p += 128) {  // rel hidden layer
        int e = p >> 6, hd = p & 63;
        float a = br1[hd];
#pragma unroll
        for (int k = 0; k < 10; k++) a += ein[e][k] * Wr1[k * RH + hd];
        hid[e][hd] = fmaxf(a, 0.f);
    }
    __syncthreads();
    // preload the 16 neighbor-feature gathers (overlap L2 latency)
    float fj[KNN];
#pragma unroll
    for (int e = 0; e < KNN; e++) fj[e] = feats[idx[e] * FDIM + t];
    float br2v = br2[t];
    float acc = 0.f;
#pragma unroll 4
    for (int e = 0; e < KNN; e++) {
        const float4* hp = (const float4*)(&hid[e][0]);
        const float4* sp = (const float4*)(&satt[e][0]);
        float ew = br2v;
#pragma unroll
        for (int k4 = 0; k4 < RH / 4; k4++) {
            float4 h4 = hp[k4];
            ew += h4.x * wreg[k4 * 4 + 0] + h4.y * wreg[k4 * 4 + 1]
                + h4.z * wreg[k4 * 4 + 2] + h4.w * wreg[k4 * 4 + 3];
        }
        float ctx = 0.f;
#pragma unroll
        for (int l4 = 0; l4 < 4; l4++) {
            float4 s4 = sp[l4];
            ctx += s4.x * lsreg[l4 * 4 + 0] + s4.y * lsreg[l4 * 4 + 1]
                 + s4.z * lsreg[l4 * 4 + 2] + s4.w * lsreg[l4 * 4 + 3];
        }
        acc += fj[e] * ctx * ew;
    }
    out[i * FDIM + t] = feats[i * FDIM + t] + acc;
}

extern "C" void kernel_launch(void* const* d_in, const int* in_sizes, int n_in,
                              void* d_out, int out_size, void* d_ws, size_t ws_size,
                              hipStream_t stream) {
    const float* xyz   = (const float*)d_in[0];
    // d_in[1] = batch_index (int32) — layout-implied (i>>10), unused
    const float* features = (const float*)d_in[2];
    const float* lang_f   = (const float*)d_in[3];
    const float* mask     = (const float*)d_in[4];
    const float* W1   = (const float*)d_in[5];
    const float* b1   = (const float*)d_in[6];
    const float* ln_g = (const float*)d_in[7];
    const float* ln_b = (const float*)d_in[8];
    const float* W2   = (const float*)d_in[9];
    const float* b2   = (const float*)d_in[10];
    const float* Wl1  = (const float*)d_in[11];
    const float* bl1  = (const float*)d_in[12];
    const float* bn_g = (const float*)d_in[13];
    const float* bn_b = (const float*)d_in[14];
    const float* Wl2  = (const float*)d_in[15];
    const float* bl2  = (const float*)d_in[16];
    const float* Wr1  = (const float*)d_in[17];
    const float* br1  = (const float*)d_in[18];
    const float* Wr2  = (const float*)d_in[19];
    const float* br2  = (const float*)d_in[20];

    float* ws_feats = (float*)d_ws;                       // N*F
    float* ws_atten = ws_feats + N_PTS * FDIM;            // N*L
    float* ws_lang  = ws_atten + N_PTS * L_TOK;           // B*L*F
    float* ws_hl    = ws_lang + B_SZ * L_TOK * FDIM;      // 64*F
    int*   ws_knn   = (int*)(ws_hl + 64 * FDIM);          // N*K

    k1_kernel<<<2112, 256, 0, stream>>>(xyz, features, lang_f,
                                        W1, b1, ln_g, ln_b, W2, b2,
                                        Wl1, bl1, ws_knn, ws_feats, ws_hl);
    lang2_kernel<<<16, 128, 0, stream>>>(ws_hl, bn_g, bn_b, Wl2, bl2, ws_lang);
    atten_kernel<<<N_PTS / 2, 256, 0, stream>>>(ws_feats, ws_lang, ws_atten);
    edge_kernel<<<N_PTS, 128, 0, stream>>>(xyz, mask, Wr1, br1, Wr2, br2,
                                           ws_knn, ws_lang, ws_feats, ws_atten,
                                           (float*)d_out);
}

// Round 4
// 165.737 us; speedup vs baseline: 1.4761x; 1.1735x over previous
//
#include <hip/hip_runtime.h>

typedef unsigned long long u64;
typedef short short8 __attribute__((ext_vector_type(8)));
typedef float f32x4 __attribute__((ext_vector_type(4)));

#define N_PTS   4096
#define B_SZ    4
#define N_PER_B 1024
#define L_TOK   16
#define FV      256
#define FL      768
#define FDIM    128
#define KNN     16
#define RH      64   // rel_encoder hidden

__device__ __forceinline__ short f2bf(float f) {
    unsigned int x = __float_as_uint(f);
    unsigned int r = (x + 0x7fffu + ((x >> 16) & 1u)) >> 16;
    return (short)r;
}

// =====================================================================
// K1: fused independent work. 256-thread blocks, specialized by range:
//   [0,1024)     knn, 4 queries/block (one wave each)
//   [1024,2048)  feat encoder, 4 points/block
//   [2048,2112)  lang encoder stage 1, 1 row/block (split-k 2)
// =====================================================================
__global__ __launch_bounds__(256) void k1_kernel(const float* __restrict__ xyz,
                                                 const float* __restrict__ features,
                                                 const float* __restrict__ lf,
                                                 const float* __restrict__ W1,
                                                 const float* __restrict__ b1,
                                                 const float* __restrict__ ln_g,
                                                 const float* __restrict__ ln_b,
                                                 const float* __restrict__ W2,
                                                 const float* __restrict__ b2,
                                                 const float* __restrict__ Wl1,
                                                 const float* __restrict__ bl1,
                                                 int* __restrict__ knn,
                                                 float* __restrict__ feats,
                                                 float* __restrict__ hl) {
    __shared__ float smem[4 * 256 + 4 * 128 + 16];
    int b = blockIdx.x, t = threadIdx.x;

    if (b < 1024) {
        // ---------------- kNN: one wave per query ----------------
        int lane = t & 63;
        int q = b * 4 + (t >> 6);
        int base = (q >> 10) << 10;
        float qx = xyz[q * 3 + 0];
        float qy = xyz[q * 3 + 1];
        float qz = xyz[q * 3 + 2];
        u64 keys[16];
#pragma unroll
        for (int m = 0; m < 16; m++) {
            int j = base + lane + (m << 6);
            float dx = qx - xyz[j * 3 + 0];
            float dy = qy - xyz[j * 3 + 1];
            float dz = qz - xyz[j * 3 + 2];
            // match reference rounding: no fma contraction, (x+y) then +z
            float d2 = __fadd_rn(__fadd_rn(__fmul_rn(dx, dx), __fmul_rn(dy, dy)),
                                 __fmul_rn(dz, dz));
            keys[m] = (((u64)__float_as_uint(d2)) << 32) | (unsigned int)j;
        }
        for (int r = 0; r < KNN; r++) {
            u64 lmin = keys[0];
#pragma unroll
            for (int m = 1; m < 16; m++) lmin = (keys[m] < lmin) ? keys[m] : lmin;
            u64 g = lmin;
#pragma unroll
            for (int off = 32; off > 0; off >>= 1) {
                u64 o = __shfl_xor(g, off, 64);
                g = (o < g) ? o : g;
            }
#pragma unroll
            for (int m = 0; m < 16; m++)
                if (keys[m] == g) keys[m] = ~0ULL;
            if (lane == 0) knn[q * KNN + r] = (int)(g & 0xffffffffu);
        }
    } else if (b < 2048) {
        // ---------------- feat encoder: 4 points/block ----------------
        int i0 = (b - 1024) * 4;
        float* fin  = smem;              // [4][256]
        float* rbuf = smem + 1024;       // [4][128]
        float* red  = smem + 1536;       // [4 waves][4]
        for (int p = t; p < 4 * FV; p += 256) {
            int pp = p >> 8, k = p & 255;
            fin[pp * FV + k] = features[(i0 + pp) * FV + k];
        }
        __syncthreads();
        int c = t & 127, h = t >> 7;
        int p0 = 2 * h, p1 = 2 * h + 1;
        float bv = b1[c];
        float acc0 = bv, acc1 = bv;
        for (int k = 0; k < FV; k++) {
            float w = W1[k * FDIM + c];
            acc0 += fin[p0 * FV + k] * w;
            acc1 += fin[p1 * FV + k] * w;
        }
        // LayerNorm over the 128 columns of each point (2 waves per half)
        float s0 = acc0, q0 = acc0 * acc0, s1 = acc1, q1 = acc1 * acc1;
#pragma unroll
        for (int off = 32; off > 0; off >>= 1) {
            s0 += __shfl_xor(s0, off, 64);
            q0 += __shfl_xor(q0, off, 64);
            s1 += __shfl_xor(s1, off, 64);
            q1 += __shfl_xor(q1, off, 64);
        }
        int wid = t >> 6;
        if ((t & 63) == 0) {
            red[wid * 4 + 0] = s0; red[wid * 4 + 1] = q0;
            red[wid * 4 + 2] = s1; red[wid * 4 + 3] = q1;
        }
        __syncthreads();
        float S0 = red[(2 * h) * 4 + 0] + red[(2 * h + 1) * 4 + 0];
        float Q0 = red[(2 * h) * 4 + 1] + red[(2 * h + 1) * 4 + 1];
        float S1 = red[(2 * h) * 4 + 2] + red[(2 * h + 1) * 4 + 2];
        float Q1 = red[(2 * h) * 4 + 3] + red[(2 * h + 1) * 4 + 3];
        float g = ln_g[c], bb = ln_b[c];
        float mu0 = S0 * (1.f / 128.f), var0 = Q0 * (1.f / 128.f) - mu0 * mu0;
        float mu1 = S1 * (1.f / 128.f), var1 = Q1 * (1.f / 128.f) - mu1 * mu1;
        float r0 = fmaxf((acc0 - mu0) * rsqrtf(var0 + 1e-5f) * g + bb, 0.f);
        float r1 = fmaxf((acc1 - mu1) * rsqrtf(var1 + 1e-5f) * g + bb, 0.f);
        rbuf[p0 * FDIM + c] = r0;
        rbuf[p1 * FDIM + c] = r1;
        __syncthreads();
        float b2v = b2[c];
        float f0 = b2v, f1 = b2v;
        for (int k = 0; k < FDIM; k++) {
            float w = W2[k * FDIM + c];
            f0 += rbuf[p0 * FDIM + k] * w;
            f1 += rbuf[p1 * FDIM + k] * w;
        }
        feats[(i0 + p0) * FDIM + c] = f0;
        feats[(i0 + p1) * FDIM + c] = f1;
    } else {
        // ---------------- lang stage 1: hl = lang_row @ Wl1 + bl1 ------
        int r = b - 2048;
        float* lrow = smem;          // [768]
        float* part = smem + 768;    // [2][128]
        for (int k = t; k < FL; k += 256) lrow[k] = lf[r * FL + k];
        __syncthreads();
        int c = t & 127, kh = t >> 7;
        float acc = (kh == 0) ? bl1[c] : 0.f;
        int k0 = kh * 384;
        for (int k = k0; k < k0 + 384; k++) acc += lrow[k] * Wl1[k * FDIM + c];
        part[kh * FDIM + c] = acc;
        __syncthreads();
        if (kh == 0) hl[r * FDIM + c] = part[c] + part[FDIM + c];
    }
}

// =====================================================================
// K2: lang stage 2 — BN (batch stats) + ReLU + GEMM2. 16 blocks × 4 rows.
// =====================================================================
__global__ __launch_bounds__(128) void lang2_kernel(const float* __restrict__ hl,
                                                    const float* __restrict__ bn_g,
                                                    const float* __restrict__ bn_b,
                                                    const float* __restrict__ Wl2,
                                                    const float* __restrict__ bl2,
                                                    float* __restrict__ lang) {
    __shared__ float rl4[4][FDIM];
    int t = threadIdx.x;
    int r0 = blockIdx.x * 4;
    float s = 0.f, s2 = 0.f;
    for (int r = 0; r < 64; r++) {
        float v = hl[r * FDIM + t];
        s += v; s2 += v * v;
    }
    float mu = s * (1.f / 64.f);
    float var = s2 * (1.f / 64.f) - mu * mu;
    float rs = rsqrtf(var + 1e-5f);
    float g = bn_g[t], bb = bn_b[t];
#pragma unroll
    for (int p = 0; p < 4; p++)
        rl4[p][t] = fmaxf((hl[(r0 + p) * FDIM + t] - mu) * rs * g + bb, 0.f);
    __syncthreads();
    float bv = bl2[t];
    float a0 = bv, a1 = bv, a2 = bv, a3 = bv;
    for (int k = 0; k < FDIM; k++) {
        float w = Wl2[k * FDIM + t];
        a0 += rl4[0][k] * w;
        a1 += rl4[1][k] * w;
        a2 += rl4[2][k] * w;
        a3 += rl4[3][k] * w;
    }
    lang[(r0 + 0) * FDIM + t] = a0;
    lang[(r0 + 1) * FDIM + t] = a1;
    lang[(r0 + 2) * FDIM + t] = a2;
    lang[(r0 + 3) * FDIM + t] = a3;
}

// =====================================================================
// K3: attention logits atten[i,l] = feats_i · lang[b_i, l]. 2 points/block.
// =====================================================================
__global__ __launch_bounds__(256) void atten_kernel(const float* __restrict__ feats,
                                                    const float* __restrict__ lang,
                                                    float* __restrict__ atten) {
    __shared__ float fb[2][FDIM];
    __shared__ float pb[256];
    int t = threadIdx.x;
    int half = t >> 7, tt = t & 127;
    int i = blockIdx.x * 2 + half;
    fb[half][tt] = feats[i * FDIM + tt];
    __syncthreads();
    int l = tt >> 3, sj = tt & 7;
    int bi = i >> 10;
    const float* lrow = lang + (bi * L_TOK + l) * FDIM;
    float p = 0.f;
#pragma unroll
    for (int m = 0; m < 16; m++) {
        int k = sj + (m << 3);
        p += fb[half][k] * lrow[k];
    }
    pb[t] = p;
    __syncthreads();
    if (tt < L_TOK) {
        float a = 0.f;
#pragma unroll
        for (int u = 0; u < 8; u++) a += pb[half * 128 + tt * 8 + u];
        atten[i * L_TOK + tt] = a;
    }
}

// =====================================================================
// K4: edge kernel v3 — ONE QUERY PER WAVE, zero LDS, zero barriers.
// Softmax via 16-lane shuffle groups; ew (16x64 @ 64x128) and
// ctx (16x16 @ 16x128, K zero-padded to 32) via bf16 MFMA 16x16x32.
// A[m=lane&15][k=quad*8+j]; B[k=quad*8+j][n=lane&15];
// C col=lane&15, row=quad*4+reg.
// =====================================================================
__global__ __launch_bounds__(256) void edge_kernel(const float* __restrict__ xyz,
                                                   const float* __restrict__ mask,
                                                   const float* __restrict__ Wr1,
                                                   const float* __restrict__ br1,
                                                   const float* __restrict__ Wr2,
                                                   const float* __restrict__ br2,
                                                   const int* __restrict__ knn,
                                                   const float* __restrict__ lang,
                                                   const float* __restrict__ feats,
                                                   const float* __restrict__ atten,
                                                   float* __restrict__ out) {
    int lane = threadIdx.x & 63;
    int wid  = threadIdx.x >> 6;
    int i    = blockIdx.x * 4 + wid;          // query
    int bi   = i >> 10;
    int quad = lane >> 4;
    int e16  = lane & 15;

    // neighbor index for e = lane&15 (same across quads)
    int idxe = knn[i * KNN + e16];

    // ---- gather logits: this lane holds l = quad*8 + j (quads 0,1 real) ----
    float sat[8];
    if (quad < 2) {
        const float4* ap = (const float4*)(atten + idxe * L_TOK + quad * 8);
        float4 a0 = ap[0], a1 = ap[1];
        sat[0] = a0.x; sat[1] = a0.y; sat[2] = a0.z; sat[3] = a0.w;
        sat[4] = a1.x; sat[5] = a1.y; sat[6] = a1.z; sat[7] = a1.w;
    } else {
#pragma unroll
        for (int j = 0; j < 8; j++) sat[j] = 0.f;
    }

    // ---- segment softmax over e (16-lane shuffle groups; quads independent)
    float mx[8];
#pragma unroll
    for (int j = 0; j < 8; j++) mx[j] = sat[j];
#pragma unroll
    for (int off = 1; off < 16; off <<= 1) {
#pragma unroll
        for (int j = 0; j < 8; j++) mx[j] = fmaxf(mx[j], __shfl_xor(mx[j], off, 16));
    }
    float ex[8], sm[8];
#pragma unroll
    for (int j = 0; j < 8; j++) { ex[j] = __expf(sat[j] - mx[j]); sm[j] = ex[j]; }
#pragma unroll
    for (int off = 1; off < 16; off <<= 1) {
#pragma unroll
        for (int j = 0; j < 8; j++) sm[j] += __shfl_xor(sm[j], off, 16);
    }
    float st[8];
    if (quad < 2) {
        const float4* mp = (const float4*)(mask + i * L_TOK + quad * 8);
        float4 m0 = mp[0], m1 = mp[1];
        float mv[8] = {m0.x, m0.y, m0.z, m0.w, m1.x, m1.y, m1.z, m1.w};
#pragma unroll
        for (int j = 0; j < 8; j++) st[j] = ex[j] * (mv[j] / sm[j]);
    } else {
#pragma unroll
        for (int j = 0; j < 8; j++) st[j] = 0.f;
    }
    // per-e normalization over l (sum across the two real quads)
    float s = st[0] + st[1] + st[2] + st[3] + st[4] + st[5] + st[6] + st[7];
    s += __shfl_xor(s, 16, 64);
    s += __shfl_xor(s, 32, 64);
    float inv2 = 1.f / (s + 1e-7f);
    short8 sattA;
#pragma unroll
    for (int j = 0; j < 8; j++) sattA[j] = f2bf(st[j] * inv2);

    // ---- rel_encoder hidden layer: hid[e=lane&15][k = s*32+quad*8+j] ----
    float xi0 = xyz[i * 3 + 0], xi1 = xyz[i * 3 + 1], xi2 = xyz[i * 3 + 2];
    float xj0 = xyz[idxe * 3 + 0], xj1 = xyz[idxe * 3 + 1], xj2 = xyz[idxe * 3 + 2];
    float d0 = xi0 - xj0, d1 = xi1 - xj1, d2v = xi2 - xj2;
    float nr = sqrtf(d0 * d0 + d1 * d1 + d2v * d2v + 1e-12f);
    float ein[10] = {xi0, xi1, xi2, xj0, xj1, xj2, d0, d1, d2v, nr};
    short8 hidA[2];
#pragma unroll
    for (int sstep = 0; sstep < 2; sstep++) {
        int k0 = sstep * 32 + quad * 8;
        float h[8];
        const float4* bp = (const float4*)(br1 + k0);
        float4 b0 = bp[0], b1v = bp[1];
        h[0] = b0.x; h[1] = b0.y; h[2] = b0.z; h[3] = b0.w;
        h[4] = b1v.x; h[5] = b1v.y; h[6] = b1v.z; h[7] = b1v.w;
#pragma unroll
        for (int m = 0; m < 10; m++) {
            const float4* wp = (const float4*)(Wr1 + m * RH + k0);
            float4 w0 = wp[0], w1 = wp[1];
            float em = ein[m];
            h[0] += em * w0.x; h[1] += em * w0.y; h[2] += em * w0.z; h[3] += em * w0.w;
            h[4] += em * w1.x; h[5] += em * w1.y; h[6] += em * w1.z; h[7] += em * w1.w;
        }
#pragma unroll
        for (int j = 0; j < 8; j++) hidA[sstep][j] = f2bf(fmaxf(h[j], 0.f));
    }

    // row (e) indices for the C-layout gathers: e = quad*4 + r
    int idxr[4];
#pragma unroll
    for (int r = 0; r < 4; r++) idxr[r] = knn[i * KNN + quad * 4 + r];

    // ---- per c-tile: ew MFMA (2 steps) + ctx MFMA (1 padded step) ----
#pragma unroll 2
    for (int tile = 0; tile < 8; tile++) {
        int cc = tile * 16 + e16;   // this lane's column
        f32x4 accew = {0.f, 0.f, 0.f, 0.f};
#pragma unroll
        for (int sstep = 0; sstep < 2; sstep++) {
            short8 w2B;
#pragma unroll
            for (int j = 0; j < 8; j++)
                w2B[j] = f2bf(Wr2[(sstep * 32 + quad * 8 + j) * FDIM + cc]);
            accew = __builtin_amdgcn_mfma_f32_16x16x32_bf16(hidA[sstep], w2B, accew, 0, 0, 0);
        }
        short8 lsB;
        if (quad < 2) {
#pragma unroll
            for (int j = 0; j < 8; j++)
                lsB[j] = f2bf(lang[bi * L_TOK * FDIM + (quad * 8 + j) * FDIM + cc]);
        } else {
#pragma unroll
            for (int j = 0; j < 8; j++) lsB[j] = 0;
        }
        f32x4 accctx = {0.f, 0.f, 0.f, 0.f};
        accctx = __builtin_amdgcn_mfma_f32_16x16x32_bf16(sattA, lsB, accctx, 0, 0, 0);

        float br2c = br2[cc];
        float msum = 0.f;
#pragma unroll
        for (int r = 0; r < 4; r++) {
            float fj = feats[idxr[r] * FDIM + cc];
            msum += fj * accctx[r] * (accew[r] + br2c);
        }
        msum += __shfl_xor(msum, 16, 64);
        msum += __shfl_xor(msum, 32, 64);
        if (lane < 16)
            out[i * FDIM + cc] = feats[i * FDIM + cc] + msum;
    }
}

extern "C" void kernel_launch(void* const* d_in, const int* in_sizes, int n_in,
                              void* d_out, int out_size, void* d_ws, size_t ws_size,
                              hipStream_t stream) {
    const float* xyz   = (const float*)d_in[0];
    // d_in[1] = batch_index (int32) — layout-implied (i>>10), unused
    const float* features = (const float*)d_in[2];
    const float* lang_f   = (const float*)d_in[3];
    const float* mask     = (const float*)d_in[4];
    const float* W1   = (const float*)d_in[5];
    const float* b1   = (const float*)d_in[6];
    const float* ln_g = (const float*)d_in[7];
    const float* ln_b = (const float*)d_in[8];
    const float* W2   = (const float*)d_in[9];
    const float* b2   = (const float*)d_in[10];
    const float* Wl1  = (const float*)d_in[11];
    const float* bl1  = (const float*)d_in[12];
    const float* bn_g = (const float*)d_in[13];
    const float* bn_b = (const float*)d_in[14];
    const float* Wl2  = (const float*)d_in[15];
    const float* bl2  = (const float*)d_in[16];
    const float* Wr1  = (const float*)d_in[17];
    const float* br1  = (const float*)d_in[18];
    const float* Wr2  = (const float*)d_in[19];
    const float* br2  = (const float*)d_in[20];

    float* ws_feats = (float*)d_ws;                       // N*F
    float* ws_atten = ws_feats + N_PTS * FDIM;            // N*L
    float* ws_lang  = ws_atten + N_PTS * L_TOK;           // B*L*F
    float* ws_hl    = ws_lang + B_SZ * L_TOK * FDIM;      // 64*F
    int*   ws_knn   = (int*)(ws_hl + 64 * FDIM);          // N*K

    k1_kernel<<<2112, 256, 0, stream>>>(xyz, features, lang_f,
                                        W1, b1, ln_g, ln_b, W2, b2,
                                        Wl1, bl1, ws_knn, ws_feats, ws_hl);
    lang2_kernel<<<16, 128, 0, stream>>>(ws_hl, bn_g, bn_b, Wl2, bl2, ws_lang);
    atten_kernel<<<N_PTS / 2, 256, 0, stream>>>(ws_feats, ws_lang, ws_atten);
    edge_kernel<<<N_PTS / 4, 256, 0, stream>>>(xyz, mask, Wr1, br1, Wr2, br2,
                                               ws_knn, ws_lang, ws_feats, ws_atten,
                                               (float*)d_out);
}